// Round 1
// baseline (586.348 us; speedup 1.0000x reference)
//
#include <hip/hip_runtime.h>

typedef float f32x4 __attribute__((ext_vector_type(4)));
typedef __bf16 bf16x8 __attribute__((ext_vector_type(8)));

#define D_MODEL 1024
#define SEQ     2048
#define NB      2
#define NH      16
#define DK      64

__device__ __forceinline__ unsigned short f2bf(float f) {
    union { float f; unsigned int u; } un; un.f = f;
    unsigned int r = un.u + 0x7fffu + ((un.u >> 16) & 1u);
    return (unsigned short)(r >> 16);
}

__device__ __forceinline__ void gload16(const void* g, void* l) {
    __builtin_amdgcn_global_load_lds((__attribute__((address_space(1))) void*)g,
                                     (__attribute__((address_space(3))) void*)l,
                                     16, 0, 0);
}

// ---------------------------------------------------------------------------
// fused fp32 -> bf16 casts for x and the 4 weight matrices
// ---------------------------------------------------------------------------
__global__ __launch_bounds__(256) void cast5(
    const float* __restrict__ x,  const float* __restrict__ wq,
    const float* __restrict__ wk, const float* __restrict__ wv,
    const float* __restrict__ wo,
    unsigned short* __restrict__ xb,  unsigned short* __restrict__ wqb,
    unsigned short* __restrict__ wkb, unsigned short* __restrict__ wvb,
    unsigned short* __restrict__ wob)
{
    const float* src; unsigned short* dst; int n8;
    switch (blockIdx.y) {
        case 0:  src = x;  dst = xb;  n8 = (NB*SEQ*D_MODEL)/8; break;
        case 1:  src = wq; dst = wqb; n8 = (D_MODEL*D_MODEL)/8; break;
        case 2:  src = wk; dst = wkb; n8 = (D_MODEL*D_MODEL)/8; break;
        case 3:  src = wv; dst = wvb; n8 = (D_MODEL*D_MODEL)/8; break;
        default: src = wo; dst = wob; n8 = (D_MODEL*D_MODEL)/8; break;
    }
    int stride = gridDim.x * blockDim.x;
    for (int i = blockIdx.x * blockDim.x + threadIdx.x; i < n8; i += stride) {
        const float4* p = (const float4*)src + (size_t)i * 2;
        float4 a = p[0], b = p[1];
        union { unsigned short h[8]; uint4 v; } u;
        u.h[0] = f2bf(a.x); u.h[1] = f2bf(a.y); u.h[2] = f2bf(a.z); u.h[3] = f2bf(a.w);
        u.h[4] = f2bf(b.x); u.h[5] = f2bf(b.y); u.h[6] = f2bf(b.z); u.h[7] = f2bf(b.w);
        ((uint4*)dst)[i] = u.v;
    }
}

// ---------------------------------------------------------------------------
// GEMM  C[M][1024] = A[M][K](bf16) * B[1024][K]^T (bf16, weights are [out][in])
// MODE 0: plain fp32 write to outF
// MODE 1: QKV fused (blockIdx.z picks weight): RoPE on Q(z=0,scaled 1/8) and
//         K(z=1), layout [bh][s][64]; V(z=2) transposed to [bh][64][s].
// 128x128 tile, BK=32, 4 waves (2x2), global_load_lds staging.
// ---------------------------------------------------------------------------
template <int MODE>
__global__ __launch_bounds__(256) void gemm_bt(
    const unsigned short* __restrict__ A,
    const unsigned short* __restrict__ B0,
    const unsigned short* __restrict__ B1,
    const unsigned short* __restrict__ B2,
    float* __restrict__ outF,
    unsigned short* __restrict__ Qh,
    unsigned short* __restrict__ Kh,
    unsigned short* __restrict__ Vt,
    int M, int K)
{
    __shared__ unsigned short As[128 * 32];
    __shared__ unsigned short Bs[128 * 32];

    const int lane = threadIdx.x & 63;
    const int wid  = threadIdx.x >> 6;
    const int m0 = blockIdx.y * 128;
    const int n0 = blockIdx.x * 128;
    const int z  = (MODE == 1) ? (int)blockIdx.z : 0;
    const unsigned short* B = (z == 0) ? B0 : (z == 1) ? B1 : B2;
    const int waveM = (wid >> 1) * 64;
    const int waveN = (wid & 1) * 64;

    f32x4 acc[4][4];
    f32x4 zero = {0.f, 0.f, 0.f, 0.f};
#pragma unroll
    for (int m = 0; m < 4; ++m)
#pragma unroll
        for (int n = 0; n < 4; ++n) acc[m][n] = zero;

    const int lrow = lane >> 2;       // 0..15 row within 16-row staging chunk
    const int lcol = (lane & 3) * 8;  // element offset 0/8/16/24 within row

    for (int k0 = 0; k0 < K; k0 += 32) {
#pragma unroll
        for (int q = 0; q < 2; ++q) {
            int rbase = wid * 32 + q * 16;
            const unsigned short* gA = A + (size_t)(m0 + rbase + lrow) * K + k0 + lcol;
            gload16(gA, (char*)As + rbase * 64);
            const unsigned short* gB = B + (size_t)(n0 + rbase + lrow) * K + k0 + lcol;
            gload16(gB, (char*)Bs + rbase * 64);
        }
        __syncthreads();
        bf16x8 af[4], bfr[4];
#pragma unroll
        for (int m = 0; m < 4; ++m)
            af[m] = *(const bf16x8*)(As + (waveM + m * 16 + (lane & 15)) * 32 + (lane >> 4) * 8);
#pragma unroll
        for (int n = 0; n < 4; ++n)
            bfr[n] = *(const bf16x8*)(Bs + (waveN + n * 16 + (lane & 15)) * 32 + (lane >> 4) * 8);
#pragma unroll
        for (int m = 0; m < 4; ++m)
#pragma unroll
            for (int n = 0; n < 4; ++n)
                acc[m][n] = __builtin_amdgcn_mfma_f32_16x16x32_bf16(af[m], bfr[n], acc[m][n], 0, 0, 0);
        __syncthreads();
    }

    if (MODE == 0) {
#pragma unroll
        for (int n = 0; n < 4; ++n) {
            int col = n0 + waveN + n * 16 + (lane & 15);
#pragma unroll
            for (int m = 0; m < 4; ++m) {
                int rowb = m0 + waveM + m * 16 + ((lane >> 4) << 2);
#pragma unroll
                for (int r = 0; r < 4; ++r)
                    outF[(size_t)(rowb + r) * D_MODEL + col] = acc[m][n][r];
            }
        }
    } else {
#pragma unroll
        for (int n = 0; n < 4; ++n) {
            int col = n0 + waveN + n * 16 + (lane & 15);
            int hh = col >> 6, dd = col & 63;
            float freq = exp2f(-0.41524101186f * (float)(dd >> 1)); // 10000^(-p/32)
#pragma unroll
            for (int m = 0; m < 4; ++m) {
                int rowb = m0 + waveM + m * 16 + ((lane >> 4) << 2);
#pragma unroll
                for (int r = 0; r < 4; ++r) {
                    float v  = acc[m][n][r];
                    float pv = __shfl_xor(v, 1);  // RoPE pair partner (col^1)
                    int row = rowb + r;
                    int bb = row >> 11, ss = row & (SEQ - 1);
                    size_t bhh = (size_t)(bb * NH + hh);
                    if (z == 2) {
                        Vt[(bhh * DK + dd) * SEQ + ss] = f2bf(v);
                    } else {
                        float sn, cs;
                        sincosf((float)ss * freq, &sn, &cs);
                        float o = (col & 1) ? (pv * sn + v * cs) : (v * cs - pv * sn);
                        if (z == 0) o *= 0.125f;  // fold 1/sqrt(DK) into Q
                        unsigned short* dst = (z == 0) ? Qh : Kh;
                        dst[(bhh * SEQ + ss) * DK + dd] = f2bf(o);
                    }
                }
            }
        }
    }
}

// ---------------------------------------------------------------------------
// causal flash attention: 1 block = 64 q rows of one (b,h); 4 waves x 16 rows.
// K/V fragments read straight from global (L2-resident). P via padded LDS.
// Qh/Kh: [bh][s][64] bf16 (Q pre-scaled by 1/8); Vt: [bh][64][s] bf16.
// Out: attn [b*2048+s][h*64+d] bf16.
// ---------------------------------------------------------------------------
__global__ __launch_bounds__(256) void attn_kernel(
    const unsigned short* __restrict__ Qh,
    const unsigned short* __restrict__ Kh,
    const unsigned short* __restrict__ Vt,
    unsigned short* __restrict__ O)
{
    __shared__ unsigned short P[4][16][72];  // 144B row stride -> 2-way bank alias only
    const int lane = threadIdx.x & 63;
    const int wid  = threadIdx.x >> 6;
    const int qt = blockIdx.x;       // q tile (64 rows)
    const int bh = blockIdx.y;       // b*16+h
    const int b = bh >> 4, h = bh & 15;
    const int q0 = qt * 64;
    const int qw = q0 + wid * 16;

    const unsigned short* Qb = Qh + (size_t)bh * SEQ * DK;
    const unsigned short* Kb = Kh + (size_t)bh * SEQ * DK;
    const unsigned short* Vb = Vt + (size_t)bh * DK * SEQ;

    bf16x8 qf[2];
#pragma unroll
    for (int kk = 0; kk < 2; ++kk)
        qf[kk] = *(const bf16x8*)(Qb + (size_t)(qw + (lane & 15)) * DK + kk * 32 + (lane >> 4) * 8);

    f32x4 zero = {0.f, 0.f, 0.f, 0.f};
    f32x4 oacc[4];
#pragma unroll
    for (int n = 0; n < 4; ++n) oacc[n] = zero;
    float mrow[4] = {-1e30f, -1e30f, -1e30f, -1e30f};
    float lrow[4] = {0.f, 0.f, 0.f, 0.f};

    for (int kt = 0; kt <= qt; ++kt) {
        int kv0 = kt * 64;
        f32x4 s[4];
#pragma unroll
        for (int n = 0; n < 4; ++n) s[n] = zero;
#pragma unroll
        for (int n = 0; n < 4; ++n)
#pragma unroll
            for (int kk = 0; kk < 2; ++kk) {
                bf16x8 kf = *(const bf16x8*)(Kb + (size_t)(kv0 + n * 16 + (lane & 15)) * DK + kk * 32 + (lane >> 4) * 8);
                s[n] = __builtin_amdgcn_mfma_f32_16x16x32_bf16(qf[kk], kf, s[n], 0, 0, 0);
            }
        if (kt == qt) {  // diagonal tile: mask col > row
#pragma unroll
            for (int n = 0; n < 4; ++n) {
                int c = n * 16 + (lane & 15);
#pragma unroll
                for (int r = 0; r < 4; ++r) {
                    int rw = wid * 16 + ((lane >> 4) << 2) + r;
                    if (c > rw) s[n][r] = -1e30f;
                }
            }
        }
        float alpha[4];
#pragma unroll
        for (int r = 0; r < 4; ++r) {
            float mx = fmaxf(fmaxf(s[0][r], s[1][r]), fmaxf(s[2][r], s[3][r]));
#pragma unroll
            for (int off = 1; off < 16; off <<= 1) mx = fmaxf(mx, __shfl_xor(mx, off));
            float mn = fmaxf(mrow[r], mx);
            alpha[r] = __expf(mrow[r] - mn);
            mrow[r] = mn;
        }
#pragma unroll
        for (int n = 0; n < 4; ++n)
#pragma unroll
            for (int r = 0; r < 4; ++r)
                s[n][r] = __expf(s[n][r] - mrow[r]);
#pragma unroll
        for (int r = 0; r < 4; ++r) {
            float rs = (s[0][r] + s[1][r]) + (s[2][r] + s[3][r]);
#pragma unroll
            for (int off = 1; off < 16; off <<= 1) rs += __shfl_xor(rs, off);
            lrow[r] = lrow[r] * alpha[r] + rs;
        }
#pragma unroll
        for (int n = 0; n < 4; ++n)
#pragma unroll
            for (int r = 0; r < 4; ++r)
                oacc[n][r] *= alpha[r];
        // P -> LDS (per-wave buffer, padded stride; same-wave DS ops are in-order)
#pragma unroll
        for (int n = 0; n < 4; ++n)
#pragma unroll
            for (int r = 0; r < 4; ++r)
                P[wid][((lane >> 4) << 2) + r][n * 16 + (lane & 15)] = f2bf(s[n][r]);
        asm volatile("s_waitcnt lgkmcnt(0)" ::: "memory");
        bf16x8 pa[2];
#pragma unroll
        for (int kk = 0; kk < 2; ++kk)
            pa[kk] = *(const bf16x8*)(&P[wid][lane & 15][kk * 32 + (lane >> 4) * 8]);
#pragma unroll
        for (int n = 0; n < 4; ++n)
#pragma unroll
            for (int kk = 0; kk < 2; ++kk) {
                bf16x8 vf = *(const bf16x8*)(Vb + (size_t)(n * 16 + (lane & 15)) * SEQ + kv0 + kk * 32 + (lane >> 4) * 8);
                oacc[n] = __builtin_amdgcn_mfma_f32_16x16x32_bf16(pa[kk], vf, oacc[n], 0, 0, 0);
            }
    }
#pragma unroll
    for (int r = 0; r < 4; ++r) {
        float inv = 1.f / lrow[r];
        int row = qw + ((lane >> 4) << 2) + r;
#pragma unroll
        for (int n = 0; n < 4; ++n) {
            int d = n * 16 + (lane & 15);
            O[((size_t)(b * SEQ + row)) * D_MODEL + h * DK + d] = f2bf(oacc[n][r] * inv);
        }
    }
}

// ---------------------------------------------------------------------------
extern "C" void kernel_launch(void* const* d_in, const int* in_sizes, int n_in,
                              void* d_out, int out_size, void* d_ws, size_t ws_size,
                              hipStream_t stream)
{
    const float* x  = (const float*)d_in[0];
    const float* Wq = (const float*)d_in[1];
    const float* Wk = (const float*)d_in[2];
    const float* Wv = (const float*)d_in[3];
    const float* Wo = (const float*)d_in[4];
    float* out = (float*)d_out;

    char* ws = (char*)d_ws;
    unsigned short* xb  = (unsigned short*)(ws);                    // 8 MB (later reused as attn buffer)
    unsigned short* Wqb = (unsigned short*)(ws + ( 8ull << 20));    // 2 MB
    unsigned short* Wkb = (unsigned short*)(ws + (10ull << 20));
    unsigned short* Wvb = (unsigned short*)(ws + (12ull << 20));
    unsigned short* Wob = (unsigned short*)(ws + (14ull << 20));
    unsigned short* Qh  = (unsigned short*)(ws + (16ull << 20));    // 8 MB [bh][s][64]
    unsigned short* Kh  = (unsigned short*)(ws + (24ull << 20));    // 8 MB [bh][s][64]
    unsigned short* Vt  = (unsigned short*)(ws + (32ull << 20));    // 8 MB [bh][64][s]
    unsigned short* attn = xb;   // alias: x no longer needed after QKV GEMM

    cast5<<<dim3(512, 5), 256, 0, stream>>>(x, Wq, Wk, Wv, Wo, xb, Wqb, Wkb, Wvb, Wob);

    gemm_bt<1><<<dim3(D_MODEL / 128, (NB * SEQ) / 128, 3), 256, 0, stream>>>(
        xb, Wqb, Wkb, Wvb, nullptr, Qh, Kh, Vt, NB * SEQ, D_MODEL);

    attn_kernel<<<dim3(SEQ / 64, NB * NH), 256, 0, stream>>>(Qh, Kh, Vt, attn);

    gemm_bt<0><<<dim3(D_MODEL / 128, (NB * SEQ) / 128, 1), 256, 0, stream>>>(
        attn, Wob, Wob, Wob, out, nullptr, nullptr, nullptr, NB * SEQ, D_MODEL);
}

// Round 2
// 462.739 us; speedup vs baseline: 1.2671x; 1.2671x over previous
//
#include <hip/hip_runtime.h>

typedef float f32x4 __attribute__((ext_vector_type(4)));
typedef __bf16 bf16x8 __attribute__((ext_vector_type(8)));

#define D_MODEL 1024
#define SEQ     2048
#define NB      2
#define NH      16
#define DK      64

__device__ __forceinline__ unsigned short f2bf(float f) {
    union { float f; unsigned int u; } un; un.f = f;
    unsigned int r = un.u + 0x7fffu + ((un.u >> 16) & 1u);
    return (unsigned short)(r >> 16);
}

__device__ __forceinline__ void gload16(const void* g, void* l) {
    __builtin_amdgcn_global_load_lds((__attribute__((address_space(1))) void*)g,
                                     (__attribute__((address_space(3))) void*)l,
                                     16, 0, 0);
}

// ---------------------------------------------------------------------------
// fused fp32 -> bf16 casts for x and the 4 weight matrices
// ---------------------------------------------------------------------------
__global__ __launch_bounds__(256) void cast5(
    const float* __restrict__ x,  const float* __restrict__ wq,
    const float* __restrict__ wk, const float* __restrict__ wv,
    const float* __restrict__ wo,
    unsigned short* __restrict__ xb,  unsigned short* __restrict__ wqb,
    unsigned short* __restrict__ wkb, unsigned short* __restrict__ wvb,
    unsigned short* __restrict__ wob)
{
    const float* src; unsigned short* dst; int n8;
    switch (blockIdx.y) {
        case 0:  src = x;  dst = xb;  n8 = (NB*SEQ*D_MODEL)/8; break;
        case 1:  src = wq; dst = wqb; n8 = (D_MODEL*D_MODEL)/8; break;
        case 2:  src = wk; dst = wkb; n8 = (D_MODEL*D_MODEL)/8; break;
        case 3:  src = wv; dst = wvb; n8 = (D_MODEL*D_MODEL)/8; break;
        default: src = wo; dst = wob; n8 = (D_MODEL*D_MODEL)/8; break;
    }
    int stride = gridDim.x * blockDim.x;
    for (int i = blockIdx.x * blockDim.x + threadIdx.x; i < n8; i += stride) {
        const float4* p = (const float4*)src + (size_t)i * 2;
        float4 a = p[0], b = p[1];
        union { unsigned short h[8]; uint4 v; } u;
        u.h[0] = f2bf(a.x); u.h[1] = f2bf(a.y); u.h[2] = f2bf(a.z); u.h[3] = f2bf(a.w);
        u.h[4] = f2bf(b.x); u.h[5] = f2bf(b.y); u.h[6] = f2bf(b.z); u.h[7] = f2bf(b.w);
        ((uint4*)dst)[i] = u.v;
    }
}

// ---------------------------------------------------------------------------
// GEMM  C[M][1024] = A[M][K](bf16) * B[1024][K]^T (bf16, weights are [out][in])
// MODE 0: plain fp32 write to outF
// MODE 1: QKV fused (blockIdx.z picks weight): RoPE on Q(z=0,scaled 1/8) and
//         K(z=1), layout [bh][s][64]; V(z=2) transposed to [bh][64][s].
// 128x128 tile, BK=32, 4 waves (2x2), global_load_lds staging.
// ---------------------------------------------------------------------------
template <int MODE>
__global__ __launch_bounds__(256) void gemm_bt(
    const unsigned short* __restrict__ A,
    const unsigned short* __restrict__ B0,
    const unsigned short* __restrict__ B1,
    const unsigned short* __restrict__ B2,
    float* __restrict__ outF,
    unsigned short* __restrict__ Qh,
    unsigned short* __restrict__ Kh,
    unsigned short* __restrict__ Vt,
    int M, int K)
{
    __shared__ unsigned short As[128 * 32];
    __shared__ unsigned short Bs[128 * 32];

    const int lane = threadIdx.x & 63;
    const int wid  = threadIdx.x >> 6;
    const int m0 = blockIdx.y * 128;
    const int n0 = blockIdx.x * 128;
    const int z  = (MODE == 1) ? (int)blockIdx.z : 0;
    const unsigned short* B = (z == 0) ? B0 : (z == 1) ? B1 : B2;
    const int waveM = (wid >> 1) * 64;
    const int waveN = (wid & 1) * 64;

    f32x4 acc[4][4];
    f32x4 zero = {0.f, 0.f, 0.f, 0.f};
#pragma unroll
    for (int m = 0; m < 4; ++m)
#pragma unroll
        for (int n = 0; n < 4; ++n) acc[m][n] = zero;

    const int lrow = lane >> 2;       // 0..15 row within 16-row staging chunk
    const int lcol = (lane & 3) * 8;  // element offset 0/8/16/24 within row

    for (int k0 = 0; k0 < K; k0 += 32) {
#pragma unroll
        for (int q = 0; q < 2; ++q) {
            int rbase = wid * 32 + q * 16;
            const unsigned short* gA = A + (size_t)(m0 + rbase + lrow) * K + k0 + lcol;
            gload16(gA, (char*)As + rbase * 64);
            const unsigned short* gB = B + (size_t)(n0 + rbase + lrow) * K + k0 + lcol;
            gload16(gB, (char*)Bs + rbase * 64);
        }
        __syncthreads();
        bf16x8 af[4], bfr[4];
#pragma unroll
        for (int m = 0; m < 4; ++m)
            af[m] = *(const bf16x8*)(As + (waveM + m * 16 + (lane & 15)) * 32 + (lane >> 4) * 8);
#pragma unroll
        for (int n = 0; n < 4; ++n)
            bfr[n] = *(const bf16x8*)(Bs + (waveN + n * 16 + (lane & 15)) * 32 + (lane >> 4) * 8);
        __builtin_amdgcn_s_setprio(1);
#pragma unroll
        for (int m = 0; m < 4; ++m)
#pragma unroll
            for (int n = 0; n < 4; ++n)
                acc[m][n] = __builtin_amdgcn_mfma_f32_16x16x32_bf16(af[m], bfr[n], acc[m][n], 0, 0, 0);
        __builtin_amdgcn_s_setprio(0);
        __syncthreads();
    }

    if (MODE == 0) {
#pragma unroll
        for (int n = 0; n < 4; ++n) {
            int col = n0 + waveN + n * 16 + (lane & 15);
#pragma unroll
            for (int m = 0; m < 4; ++m) {
                int rowb = m0 + waveM + m * 16 + ((lane >> 4) << 2);
#pragma unroll
                for (int r = 0; r < 4; ++r)
                    outF[(size_t)(rowb + r) * D_MODEL + col] = acc[m][n][r];
            }
        }
    } else {
#pragma unroll
        for (int n = 0; n < 4; ++n) {
            int col = n0 + waveN + n * 16 + (lane & 15);
            int hh = col >> 6, dd = col & 63;
            float freq = exp2f(-0.41524101186f * (float)(dd >> 1)); // 10000^(-p/32)
#pragma unroll
            for (int m = 0; m < 4; ++m) {
                int rowb = m0 + waveM + m * 16 + ((lane >> 4) << 2);
#pragma unroll
                for (int r = 0; r < 4; ++r) {
                    float v  = acc[m][n][r];
                    float pv = __shfl_xor(v, 1);  // RoPE pair partner (col^1)
                    int row = rowb + r;
                    int bb = row >> 11, ss = row & (SEQ - 1);
                    size_t bhh = (size_t)(bb * NH + hh);
                    if (z == 2) {
                        Vt[(bhh * DK + dd) * SEQ + ss] = f2bf(v);
                    } else {
                        float sn, cs;
                        sincosf((float)ss * freq, &sn, &cs);
                        float o = (col & 1) ? (pv * sn + v * cs) : (v * cs - pv * sn);
                        if (z == 0) o *= 0.125f;  // fold 1/sqrt(DK) into Q
                        unsigned short* dst = (z == 0) ? Qh : Kh;
                        dst[(bhh * SEQ + ss) * DK + dd] = f2bf(o);
                    }
                }
            }
        }
    }
}

// ---------------------------------------------------------------------------
// causal flash attention v2: 1 block = 64 q rows of one (b,h); 4 waves x 16
// rows; KV tile = 128 (2x fewer iterations, 2x the load/MFMA per latency
// window). Longest q-tiles dispatch FIRST (grid.y reversed) to kill the
// causal-imbalance tail. Diagonal tile skips fully-masked 16-col subtiles
// (wave-uniform nlim). V loads issued before the LDS wait. setprio on MFMA.
// Qh/Kh: [bh][s][64] bf16 (Q pre-scaled by 1/8); Vt: [bh][64][s] bf16.
// ---------------------------------------------------------------------------
__global__ __launch_bounds__(256) void attn_kernel(
    const unsigned short* __restrict__ Qh,
    const unsigned short* __restrict__ Kh,
    const unsigned short* __restrict__ Vt,
    unsigned short* __restrict__ O)
{
    __shared__ unsigned short P[4][16][136];  // 272B row stride: only 2-way bank alias
    const int lane = threadIdx.x & 63;
    const int wid  = threadIdx.x >> 6;
    const int bh = blockIdx.x;                       // b*16+h
    const int qt = (int)gridDim.y - 1 - (int)blockIdx.y;  // longest tiles first
    const int b = bh >> 4, h = bh & 15;
    const int q0 = qt * 64;
    const int qw = q0 + wid * 16;
    const int ktlast = (q0 + 63) >> 7;
    const int l15 = lane & 15, lhi = lane >> 4;

    const unsigned short* Qb = Qh + (size_t)bh * SEQ * DK;
    const unsigned short* Kb = Kh + (size_t)bh * SEQ * DK;
    const unsigned short* Vb = Vt + (size_t)bh * DK * SEQ;

    bf16x8 qf[2];
#pragma unroll
    for (int kk = 0; kk < 2; ++kk)
        qf[kk] = *(const bf16x8*)(Qb + (size_t)(qw + l15) * DK + kk * 32 + lhi * 8);

    const f32x4 zero = {0.f, 0.f, 0.f, 0.f};
    const f32x4 ninf = {-1e30f, -1e30f, -1e30f, -1e30f};
    f32x4 oacc[4];
#pragma unroll
    for (int nd = 0; nd < 4; ++nd) oacc[nd] = zero;
    float mrow[4] = {-1e30f, -1e30f, -1e30f, -1e30f};
    float lrow[4] = {0.f, 0.f, 0.f, 0.f};

    for (int kt = 0; kt <= ktlast; ++kt) {
        const int kv0 = kt << 7;
        const bool diag = (kt == ktlast);
        const int nlim = diag ? (((qw - kv0) >> 4) + 1) : 8;  // valid 16-col subtiles

        f32x4 s[8];
#pragma unroll
        for (int n = 0; n < 8; ++n) s[n] = (n < nlim) ? zero : ninf;

        // ---- QK^T in two halves (caps K-fragment register pressure) ----
#pragma unroll
        for (int half = 0; half < 2; ++half) {
            bf16x8 kf[4][2];
#pragma unroll
            for (int n4 = 0; n4 < 4; ++n4) {
                int n = half * 4 + n4;
                if (n < nlim) {
#pragma unroll
                    for (int kk = 0; kk < 2; ++kk)
                        kf[n4][kk] = *(const bf16x8*)(Kb + (size_t)(kv0 + n * 16 + l15) * DK + kk * 32 + lhi * 8);
                }
            }
            __builtin_amdgcn_s_setprio(1);
#pragma unroll
            for (int n4 = 0; n4 < 4; ++n4) {
                int n = half * 4 + n4;
                if (n < nlim) {
#pragma unroll
                    for (int kk = 0; kk < 2; ++kk)
                        s[n] = __builtin_amdgcn_mfma_f32_16x16x32_bf16(qf[kk], kf[n4][kk], s[n], 0, 0, 0);
                }
            }
            __builtin_amdgcn_s_setprio(0);
        }

        if (diag) {  // element-level causal mask on the diagonal tile
#pragma unroll
            for (int n = 0; n < 8; ++n) {
                if (n < nlim) {
                    int c = kv0 + n * 16 + l15;
#pragma unroll
                    for (int r = 0; r < 4; ++r) {
                        int rw = qw + (lhi << 2) + r;
                        if (c > rw) s[n][r] = -1e30f;
                    }
                }
            }
        }

        // ---- online softmax over 128 cols (invalid cols are -1e30 -> 0) ----
        float alpha[4];
#pragma unroll
        for (int r = 0; r < 4; ++r) {
            float mx = s[0][r];
#pragma unroll
            for (int n = 1; n < 8; ++n) mx = fmaxf(mx, s[n][r]);
#pragma unroll
            for (int off = 1; off < 16; off <<= 1) mx = fmaxf(mx, __shfl_xor(mx, off));
            float mn = fmaxf(mrow[r], mx);
            alpha[r] = __expf(mrow[r] - mn);
            mrow[r] = mn;
        }
#pragma unroll
        for (int n = 0; n < 8; ++n)
#pragma unroll
            for (int r = 0; r < 4; ++r)
                s[n][r] = __expf(s[n][r] - mrow[r]);
#pragma unroll
        for (int r = 0; r < 4; ++r) {
            float rs = 0.f;
#pragma unroll
            for (int n = 0; n < 8; ++n) rs += s[n][r];
#pragma unroll
            for (int off = 1; off < 16; off <<= 1) rs += __shfl_xor(rs, off);
            lrow[r] = lrow[r] * alpha[r] + rs;
        }
#pragma unroll
        for (int nd = 0; nd < 4; ++nd)
#pragma unroll
            for (int r = 0; r < 4; ++r)
                oacc[nd][r] *= alpha[r];

        // ---- P -> LDS (per-wave buffer; same-wave DS ops are in-order) ----
#pragma unroll
        for (int n = 0; n < 8; ++n)
#pragma unroll
            for (int r = 0; r < 4; ++r)
                P[wid][(lhi << 2) + r][n * 16 + l15] = f2bf(s[n][r]);

        // ---- V loads issued before the LDS wait (overlap) ----
        const int kklim = diag ? ((nlim + 1) >> 1) : 4;
        bf16x8 vf[4][4];  // [kk][nd]
#pragma unroll
        for (int kk = 0; kk < 4; ++kk) {
            if (kk < kklim) {
#pragma unroll
                for (int nd = 0; nd < 4; ++nd)
                    vf[kk][nd] = *(const bf16x8*)(Vb + (size_t)(nd * 16 + l15) * SEQ + kv0 + kk * 32 + lhi * 8);
            }
        }

        asm volatile("s_waitcnt lgkmcnt(0)" ::: "memory");
        bf16x8 pa[4];
#pragma unroll
        for (int kk = 0; kk < 4; ++kk)
            if (kk < kklim)
                pa[kk] = *(const bf16x8*)(&P[wid][l15][kk * 32 + lhi * 8]);

        __builtin_amdgcn_s_setprio(1);
#pragma unroll
        for (int nd = 0; nd < 4; ++nd)
#pragma unroll
            for (int kk = 0; kk < 4; ++kk)
                if (kk < kklim)
                    oacc[nd] = __builtin_amdgcn_mfma_f32_16x16x32_bf16(pa[kk], vf[kk][nd], oacc[nd], 0, 0, 0);
        __builtin_amdgcn_s_setprio(0);
    }

#pragma unroll
    for (int r = 0; r < 4; ++r) {
        float inv = 1.f / lrow[r];
        int row = qw + (lhi << 2) + r;
#pragma unroll
        for (int nd = 0; nd < 4; ++nd) {
            int d = nd * 16 + l15;
            O[((size_t)(b * SEQ + row)) * D_MODEL + h * DK + d] = f2bf(oacc[nd][r] * inv);
        }
    }
}

// ---------------------------------------------------------------------------
extern "C" void kernel_launch(void* const* d_in, const int* in_sizes, int n_in,
                              void* d_out, int out_size, void* d_ws, size_t ws_size,
                              hipStream_t stream)
{
    const float* x  = (const float*)d_in[0];
    const float* Wq = (const float*)d_in[1];
    const float* Wk = (const float*)d_in[2];
    const float* Wv = (const float*)d_in[3];
    const float* Wo = (const float*)d_in[4];
    float* out = (float*)d_out;

    char* ws = (char*)d_ws;
    unsigned short* xb  = (unsigned short*)(ws);                    // 8 MB (later reused as attn buffer)
    unsigned short* Wqb = (unsigned short*)(ws + ( 8ull << 20));    // 2 MB
    unsigned short* Wkb = (unsigned short*)(ws + (10ull << 20));
    unsigned short* Wvb = (unsigned short*)(ws + (12ull << 20));
    unsigned short* Wob = (unsigned short*)(ws + (14ull << 20));
    unsigned short* Qh  = (unsigned short*)(ws + (16ull << 20));    // 8 MB [bh][s][64]
    unsigned short* Kh  = (unsigned short*)(ws + (24ull << 20));    // 8 MB [bh][s][64]
    unsigned short* Vt  = (unsigned short*)(ws + (32ull << 20));    // 8 MB [bh][64][s]
    unsigned short* attn = xb;   // alias: x no longer needed after QKV GEMM

    cast5<<<dim3(512, 5), 256, 0, stream>>>(x, Wq, Wk, Wv, Wo, xb, Wqb, Wkb, Wvb, Wob);

    gemm_bt<1><<<dim3(D_MODEL / 128, (NB * SEQ) / 128, 3), 256, 0, stream>>>(
        xb, Wqb, Wkb, Wvb, nullptr, Qh, Kh, Vt, NB * SEQ, D_MODEL);

    attn_kernel<<<dim3(NB * NH, SEQ / 64), 256, 0, stream>>>(Qh, Kh, Vt, attn);

    gemm_bt<0><<<dim3(D_MODEL / 128, (NB * SEQ) / 128, 1), 256, 0, stream>>>(
        attn, Wob, Wob, Wob, out, nullptr, nullptr, nullptr, NB * SEQ, D_MODEL);
}

// Round 3
// 204.784 us; speedup vs baseline: 2.8632x; 2.2596x over previous
//
#include <hip/hip_runtime.h>

typedef float f32x4 __attribute__((ext_vector_type(4)));
typedef __bf16 bf16x8 __attribute__((ext_vector_type(8)));

#define D_MODEL 1024
#define SEQ     2048
#define NB      2
#define NH      16
#define DK      64

__device__ __forceinline__ unsigned short f2bf(float f) {
    union { float f; unsigned int u; } un; un.f = f;
    unsigned int r = un.u + 0x7fffu + ((un.u >> 16) & 1u);
    return (unsigned short)(r >> 16);
}

__device__ __forceinline__ void gload16(const void* g, void* l) {
    __builtin_amdgcn_global_load_lds((__attribute__((address_space(1))) void*)g,
                                     (__attribute__((address_space(3))) void*)l,
                                     16, 0, 0);
}

// ---------------------------------------------------------------------------
// fused fp32 -> bf16 casts for x and the 4 weights + RoPE cos/sin table
// ---------------------------------------------------------------------------
__global__ __launch_bounds__(256) void cast5(
    const float* __restrict__ x,  const float* __restrict__ wq,
    const float* __restrict__ wk, const float* __restrict__ wv,
    const float* __restrict__ wo,
    unsigned short* __restrict__ xb,  unsigned short* __restrict__ wqb,
    unsigned short* __restrict__ wkb, unsigned short* __restrict__ wvb,
    unsigned short* __restrict__ wob, float2* __restrict__ tab)
{
    if (blockIdx.y == 5) {  // RoPE table: [ss][p] -> (cos, sin), p = d/2 index
        int idx = blockIdx.x * 256 + threadIdx.x;
        if (idx < SEQ * 32) {
            int ss = idx >> 5, p = idx & 31;
            float freq = exp2f(-0.41524101186f * (float)p);  // 10000^(-p/32)
            float sn, cs;
            sincosf((float)ss * freq, &sn, &cs);
            tab[idx] = make_float2(cs, sn);
        }
        return;
    }
    const float* src; unsigned short* dst; int n8;
    switch (blockIdx.y) {
        case 0:  src = x;  dst = xb;  n8 = (NB*SEQ*D_MODEL)/8; break;
        case 1:  src = wq; dst = wqb; n8 = (D_MODEL*D_MODEL)/8; break;
        case 2:  src = wk; dst = wkb; n8 = (D_MODEL*D_MODEL)/8; break;
        case 3:  src = wv; dst = wvb; n8 = (D_MODEL*D_MODEL)/8; break;
        default: src = wo; dst = wob; n8 = (D_MODEL*D_MODEL)/8; break;
    }
    int stride = gridDim.x * blockDim.x;
    for (int i = blockIdx.x * blockDim.x + threadIdx.x; i < n8; i += stride) {
        const float4* p = (const float4*)src + (size_t)i * 2;
        float4 a = p[0], b = p[1];
        union { unsigned short h[8]; uint4 v; } u;
        u.h[0] = f2bf(a.x); u.h[1] = f2bf(a.y); u.h[2] = f2bf(a.z); u.h[3] = f2bf(a.w);
        u.h[4] = f2bf(b.x); u.h[5] = f2bf(b.y); u.h[6] = f2bf(b.z); u.h[7] = f2bf(b.w);
        ((uint4*)dst)[i] = u.v;
    }
}

// ---------------------------------------------------------------------------
// GEMM  C[M][1024] = A[M][K](bf16) * B[1024][K]^T (bf16, weights are [out][in])
// MODE 0: plain fp32 write to outF (coalesced 256B/wave-instr)
// MODE 1: QKV fused (blockIdx.z picks weight): RoPE via table on Q(z=0,
//   scaled 1/8) and K(z=1) -> [bh][s][64]; V(z=2) transposed -> [bh][64][s].
//   Epilogue stages each wave's 64x64 bf16 tile in LDS, then stores 16B/lane
//   (full 128B lines back-to-back) to avoid HBM partial-line write blowup
//   (R2: 1.64 GB observed for 24 MB of data).
// ---------------------------------------------------------------------------
template <int MODE>
__global__ __launch_bounds__(256) void gemm_bt(
    const unsigned short* __restrict__ A,
    const unsigned short* __restrict__ B0,
    const unsigned short* __restrict__ B1,
    const unsigned short* __restrict__ B2,
    float* __restrict__ outF,
    unsigned short* __restrict__ Qh,
    unsigned short* __restrict__ Kh,
    unsigned short* __restrict__ Vt,
    const float2* __restrict__ tab,
    int M, int K)
{
    __shared__ unsigned short As[128 * 32];
    __shared__ unsigned short Bs[128 * 32];

    const int lane = threadIdx.x & 63;
    const int wid  = threadIdx.x >> 6;
    const int l15 = lane & 15, lhi = lane >> 4;
    const int m0 = blockIdx.y * 128;
    const int n0 = blockIdx.x * 128;
    const int z  = (MODE == 1) ? (int)blockIdx.z : 0;
    const unsigned short* B = (z == 0) ? B0 : (z == 1) ? B1 : B2;
    const int waveM = (wid >> 1) * 64;
    const int waveN = (wid & 1) * 64;

    f32x4 acc[4][4];
    f32x4 zero = {0.f, 0.f, 0.f, 0.f};
#pragma unroll
    for (int m = 0; m < 4; ++m)
#pragma unroll
        for (int n = 0; n < 4; ++n) acc[m][n] = zero;

    const int lrow = lane >> 2;       // 0..15 row within 16-row staging chunk
    const int lcol = (lane & 3) * 8;  // element offset 0/8/16/24 within row

    for (int k0 = 0; k0 < K; k0 += 32) {
#pragma unroll
        for (int q = 0; q < 2; ++q) {
            int rbase = wid * 32 + q * 16;
            const unsigned short* gA = A + (size_t)(m0 + rbase + lrow) * K + k0 + lcol;
            gload16(gA, (char*)As + rbase * 64);
            const unsigned short* gB = B + (size_t)(n0 + rbase + lrow) * K + k0 + lcol;
            gload16(gB, (char*)Bs + rbase * 64);
        }
        __syncthreads();
        bf16x8 af[4], bfr[4];
#pragma unroll
        for (int m = 0; m < 4; ++m)
            af[m] = *(const bf16x8*)(As + (waveM + m * 16 + l15) * 32 + lhi * 8);
#pragma unroll
        for (int n = 0; n < 4; ++n)
            bfr[n] = *(const bf16x8*)(Bs + (waveN + n * 16 + l15) * 32 + lhi * 8);
#pragma unroll
        for (int m = 0; m < 4; ++m)
#pragma unroll
            for (int n = 0; n < 4; ++n)
                acc[m][n] = __builtin_amdgcn_mfma_f32_16x16x32_bf16(af[m], bfr[n], acc[m][n], 0, 0, 0);
        __syncthreads();
    }

    if constexpr (MODE == 0) {
#pragma unroll
        for (int n = 0; n < 4; ++n) {
            int col = n0 + waveN + n * 16 + l15;
#pragma unroll
            for (int m = 0; m < 4; ++m) {
                int rowb = m0 + waveM + m * 16 + (lhi << 2);
#pragma unroll
                for (int r = 0; r < 4; ++r)
                    outF[(size_t)(rowb + r) * D_MODEL + col] = acc[m][n][r];
            }
        }
    } else {
        __shared__ unsigned short Ct[4][64][72];  // per-wave 64x64 bf16, padded
        const int colg0 = n0 + waveN;   // 64-aligned -> exactly one head
        const int hh    = (colg0 >> 6) & (NH - 1);
        const int rowg0 = m0 + waveM;   // 64-aligned, never crosses batch bound
        const int bb    = rowg0 >> 11;
        const size_t bhh = (size_t)(bb * NH + hh);

        // phase 1: RoPE + pack into LDS (Q/K row-major, V transposed)
#pragma unroll
        for (int n = 0; n < 4; ++n) {
            int cl = n * 16 + l15;      // local col = dd (head-dim index)
#pragma unroll
            for (int m = 0; m < 4; ++m) {
#pragma unroll
                for (int r = 0; r < 4; ++r) {
                    float v  = acc[m][n][r];
                    float pv = __shfl_xor(v, 1);   // RoPE pair partner (dd^1)
                    int rl = m * 16 + (lhi << 2) + r;   // local row 0..63
                    if (z == 2) {
                        Ct[wid][cl][rl] = f2bf(v);      // [dd][ss-local]
                    } else {
                        int ss = (rowg0 + rl) & (SEQ - 1);
                        float2 cs = tab[(ss << 5) + (cl >> 1)];
                        float o = (cl & 1) ? (pv * cs.y + v * cs.x)
                                           : (v * cs.x - pv * cs.y);
                        if (z == 0) o *= 0.125f;        // fold 1/sqrt(DK) into Q
                        Ct[wid][rl][cl] = f2bf(o);      // [ss-local][dd]
                    }
                }
            }
        }
        asm volatile("s_waitcnt lgkmcnt(0)" ::: "memory");

        // phase 2: 16B/lane stores -> 8 full consecutive 128B lines per instr
        const int lr = lane >> 3;         // 0..7
        const int lc = (lane & 7) << 3;   // 0..56 step 8
#pragma unroll
        for (int i = 0; i < 8; ++i) {
            int rl = i * 8 + lr;
            uint4 w = *(const uint4*)&Ct[wid][rl][lc];
            if (z == 2) {
                // rl = dd; contiguous ss run of 64 starting at rowg0's ss
                int ss0 = rowg0 & (SEQ - 1);
                *(uint4*)(Vt + (bhh * DK + rl) * SEQ + ss0 + lc) = w;
            } else {
                int ss = (rowg0 + rl) & (SEQ - 1);
                unsigned short* dst = (z == 0) ? Qh : Kh;
                *(uint4*)(dst + (bhh * SEQ + ss) * DK + lc) = w;
            }
        }
    }
}

// ---------------------------------------------------------------------------
// causal flash attention: 1 block = 64 q rows of one (b,h); 4 waves x 16
// rows; KV tile = 128. Longest q-tiles dispatch FIRST. Diagonal tile skips
// fully-masked 16-col subtiles. V loads issued before the LDS wait.
// Qh/Kh: [bh][s][64] bf16 (Q pre-scaled by 1/8); Vt: [bh][64][s] bf16.
// ---------------------------------------------------------------------------
__global__ __launch_bounds__(256) void attn_kernel(
    const unsigned short* __restrict__ Qh,
    const unsigned short* __restrict__ Kh,
    const unsigned short* __restrict__ Vt,
    unsigned short* __restrict__ O)
{
    __shared__ unsigned short P[4][16][136];  // 272B row stride: 2-way alias only
    const int lane = threadIdx.x & 63;
    const int wid  = threadIdx.x >> 6;
    const int bh = blockIdx.x;                       // b*16+h
    const int qt = (int)gridDim.y - 1 - (int)blockIdx.y;  // longest tiles first
    const int b = bh >> 4, h = bh & 15;
    const int q0 = qt * 64;
    const int qw = q0 + wid * 16;
    const int ktlast = (q0 + 63) >> 7;
    const int l15 = lane & 15, lhi = lane >> 4;

    const unsigned short* Qb = Qh + (size_t)bh * SEQ * DK;
    const unsigned short* Kb = Kh + (size_t)bh * SEQ * DK;
    const unsigned short* Vb = Vt + (size_t)bh * DK * SEQ;

    bf16x8 qf[2];
#pragma unroll
    for (int kk = 0; kk < 2; ++kk)
        qf[kk] = *(const bf16x8*)(Qb + (size_t)(qw + l15) * DK + kk * 32 + lhi * 8);

    const f32x4 zero = {0.f, 0.f, 0.f, 0.f};
    const f32x4 ninf = {-1e30f, -1e30f, -1e30f, -1e30f};
    f32x4 oacc[4];
#pragma unroll
    for (int nd = 0; nd < 4; ++nd) oacc[nd] = zero;
    float mrow[4] = {-1e30f, -1e30f, -1e30f, -1e30f};
    float lrow[4] = {0.f, 0.f, 0.f, 0.f};

    for (int kt = 0; kt <= ktlast; ++kt) {
        const int kv0 = kt << 7;
        const bool diag = (kt == ktlast);
        const int nlim = diag ? (((qw - kv0) >> 4) + 1) : 8;  // valid subtiles

        f32x4 s[8];
#pragma unroll
        for (int n = 0; n < 8; ++n) s[n] = (n < nlim) ? zero : ninf;

#pragma unroll
        for (int half = 0; half < 2; ++half) {
            bf16x8 kf[4][2];
#pragma unroll
            for (int n4 = 0; n4 < 4; ++n4) {
                int n = half * 4 + n4;
                if (n < nlim) {
#pragma unroll
                    for (int kk = 0; kk < 2; ++kk)
                        kf[n4][kk] = *(const bf16x8*)(Kb + (size_t)(kv0 + n * 16 + l15) * DK + kk * 32 + lhi * 8);
                }
            }
            __builtin_amdgcn_s_setprio(1);
#pragma unroll
            for (int n4 = 0; n4 < 4; ++n4) {
                int n = half * 4 + n4;
                if (n < nlim) {
#pragma unroll
                    for (int kk = 0; kk < 2; ++kk)
                        s[n] = __builtin_amdgcn_mfma_f32_16x16x32_bf16(qf[kk], kf[n4][kk], s[n], 0, 0, 0);
                }
            }
            __builtin_amdgcn_s_setprio(0);
        }

        if (diag) {
#pragma unroll
            for (int n = 0; n < 8; ++n) {
                if (n < nlim) {
                    int c = kv0 + n * 16 + l15;
#pragma unroll
                    for (int r = 0; r < 4; ++r) {
                        int rw = qw + (lhi << 2) + r;
                        if (c > rw) s[n][r] = -1e30f;
                    }
                }
            }
        }

        float alpha[4];
#pragma unroll
        for (int r = 0; r < 4; ++r) {
            float mx = s[0][r];
#pragma unroll
            for (int n = 1; n < 8; ++n) mx = fmaxf(mx, s[n][r]);
#pragma unroll
            for (int off = 1; off < 16; off <<= 1) mx = fmaxf(mx, __shfl_xor(mx, off));
            float mn = fmaxf(mrow[r], mx);
            alpha[r] = __expf(mrow[r] - mn);
            mrow[r] = mn;
        }
#pragma unroll
        for (int n = 0; n < 8; ++n)
#pragma unroll
            for (int r = 0; r < 4; ++r)
                s[n][r] = __expf(s[n][r] - mrow[r]);
#pragma unroll
        for (int r = 0; r < 4; ++r) {
            float rs = 0.f;
#pragma unroll
            for (int n = 0; n < 8; ++n) rs += s[n][r];
#pragma unroll
            for (int off = 1; off < 16; off <<= 1) rs += __shfl_xor(rs, off);
            lrow[r] = lrow[r] * alpha[r] + rs;
        }
#pragma unroll
        for (int nd = 0; nd < 4; ++nd)
#pragma unroll
            for (int r = 0; r < 4; ++r)
                oacc[nd][r] *= alpha[r];

#pragma unroll
        for (int n = 0; n < 8; ++n)
#pragma unroll
            for (int r = 0; r < 4; ++r)
                P[wid][(lhi << 2) + r][n * 16 + l15] = f2bf(s[n][r]);

        const int kklim = diag ? ((nlim + 1) >> 1) : 4;
        bf16x8 vf[4][4];  // [kk][nd]
#pragma unroll
        for (int kk = 0; kk < 4; ++kk) {
            if (kk < kklim) {
#pragma unroll
                for (int nd = 0; nd < 4; ++nd)
                    vf[kk][nd] = *(const bf16x8*)(Vb + (size_t)(nd * 16 + l15) * SEQ + kv0 + kk * 32 + lhi * 8);
            }
        }

        asm volatile("s_waitcnt lgkmcnt(0)" ::: "memory");
        bf16x8 pa[4];
#pragma unroll
        for (int kk = 0; kk < 4; ++kk)
            if (kk < kklim)
                pa[kk] = *(const bf16x8*)(&P[wid][l15][kk * 32 + lhi * 8]);

        __builtin_amdgcn_s_setprio(1);
#pragma unroll
        for (int nd = 0; nd < 4; ++nd)
#pragma unroll
            for (int kk = 0; kk < 4; ++kk)
                if (kk < kklim)
                    oacc[nd] = __builtin_amdgcn_mfma_f32_16x16x32_bf16(pa[kk], vf[kk][nd], oacc[nd], 0, 0, 0);
        __builtin_amdgcn_s_setprio(0);
    }

#pragma unroll
    for (int r = 0; r < 4; ++r) {
        float inv = 1.f / lrow[r];
        int row = qw + (lhi << 2) + r;
#pragma unroll
        for (int nd = 0; nd < 4; ++nd) {
            int d = nd * 16 + l15;
            O[((size_t)(b * SEQ + row)) * D_MODEL + h * DK + d] = f2bf(oacc[nd][r] * inv);
        }
    }
}

// ---------------------------------------------------------------------------
extern "C" void kernel_launch(void* const* d_in, const int* in_sizes, int n_in,
                              void* d_out, int out_size, void* d_ws, size_t ws_size,
                              hipStream_t stream)
{
    const float* x  = (const float*)d_in[0];
    const float* Wq = (const float*)d_in[1];
    const float* Wk = (const float*)d_in[2];
    const float* Wv = (const float*)d_in[3];
    const float* Wo = (const float*)d_in[4];
    float* out = (float*)d_out;

    char* ws = (char*)d_ws;
    unsigned short* xb  = (unsigned short*)(ws);                    // 8 MB (reused as attn buf)
    unsigned short* Wqb = (unsigned short*)(ws + ( 8ull << 20));
    unsigned short* Wkb = (unsigned short*)(ws + (10ull << 20));
    unsigned short* Wvb = (unsigned short*)(ws + (12ull << 20));
    unsigned short* Wob = (unsigned short*)(ws + (14ull << 20));
    unsigned short* Qh  = (unsigned short*)(ws + (16ull << 20));    // [bh][s][64]
    unsigned short* Kh  = (unsigned short*)(ws + (24ull << 20));    // [bh][s][64]
    unsigned short* Vt  = (unsigned short*)(ws + (32ull << 20));    // [bh][64][s]
    float2*         tab = (float2*)(ws + (40ull << 20));            // 512 KB RoPE table
    unsigned short* attn = xb;

    cast5<<<dim3(512, 6), 256, 0, stream>>>(x, Wq, Wk, Wv, Wo, xb, Wqb, Wkb, Wvb, Wob, tab);

    gemm_bt<1><<<dim3(D_MODEL / 128, (NB * SEQ) / 128, 3), 256, 0, stream>>>(
        xb, Wqb, Wkb, Wvb, nullptr, Qh, Kh, Vt, tab, NB * SEQ, D_MODEL);

    attn_kernel<<<dim3(NB * NH, SEQ / 64), 256, 0, stream>>>(Qh, Kh, Vt, attn);

    gemm_bt<0><<<dim3(D_MODEL / 128, (NB * SEQ) / 128, 1), 256, 0, stream>>>(
        attn, Wob, Wob, Wob, out, nullptr, nullptr, nullptr, nullptr, NB * SEQ, D_MODEL);
}